// Round 8
// baseline (11396.223 us; speedup 1.0000x reference)
//
#include <hip/hip_runtime.h>
#include <hip/hip_bf16.h>
#include <math.h>

#define D_MODEL 768
#define SEQ     197
#define BATCH   32
#define NTOK    (BATCH*SEQ)   // 6304
#define NHEAD   12
#define HDIM    64
#define NEXP    4
#define HID_N   3072
#define DEPTH_N 12

typedef __attribute__((ext_vector_type(4))) float f32x4;
typedef __attribute__((ext_vector_type(8))) short bf16x8;
typedef __attribute__((ext_vector_type(4))) unsigned short u16x4;
typedef unsigned short u16;

// fp32 -> bf16 round-to-nearest-even
static __device__ __forceinline__ u16 f2bf(float f){
  unsigned int u = __builtin_bit_cast(unsigned int, f);
  u += 0x7FFFu + ((u >> 16) & 1u);
  return (u16)(u >> 16);
}
// split x ~= hi + lo (bf16 each)
static __device__ __forceinline__ void split_bf(float x, u16& h, u16& l){
  h = f2bf(x);
  float hf = __builtin_bit_cast(float, (unsigned)h << 16);
  l = f2bf(x - hf);
}

static __device__ __forceinline__ float wred_sum(float v){
  #pragma unroll
  for (int off = 32; off; off >>= 1) v += __shfl_down(v, off);
  return v;
}

static __device__ __forceinline__ int xcd_map(int orig, int nwg){
  int q = nwg >> 3, r = nwg & 7;
  int xcd = orig & 7, idx = orig >> 3;
  return (xcd < r ? xcd*(q+1) : r*(q+1) + (xcd-r)*q) + idx;
}

// global -> LDS direct, 16 B per lane (dest wave-uniform base + lane*16)
static __device__ __forceinline__ void gld16(const u16* g, u16* l){
  __builtin_amdgcn_global_load_lds(
      (const __attribute__((address_space(1))) unsigned int*)g,
      (__attribute__((address_space(3))) unsigned int*)l, 16, 0, 0);
}

// ---------------- split converter (weights, x) ----------------
__global__ __launch_bounds__(256) void split_many(const float* __restrict__ src,
                                                  u16* __restrict__ hi,
                                                  u16* __restrict__ lo, long n4){
  for (long i = blockIdx.x*256L + threadIdx.x; i < n4; i += (long)gridDim.x*256){
    f32x4 v = *reinterpret_cast<const f32x4*>(src + i*4);
    u16x4 h, l;
    #pragma unroll
    for (int j = 0; j < 4; j++){ u16 hh, ll; split_bf(v[j], hh, ll); h[j]=hh; l[j]=ll; }
    *reinterpret_cast<u16x4*>(hi + i*4) = h;
    *reinterpret_cast<u16x4*>(lo + i*4) = l;
  }
}

// =====================================================================
// split-precision MFMA GEMM, plane inputs, global_load_lds staging.
// C = A @ W^T via Ah*Wh + Ah*Wl + Al*Wh (error ~2^-16).
// 128x128 tile, BK=32, 4 waves (2x2), 4x4 frags of 16x16x32.
// LDS: [4 planes][128x32 u16] = 32 KB SINGLE buffer -> 5 blocks/CU
// (20 waves/CU: inter-block overlap hides the barrier drains, m114).
// Chunk swizzle on global SOURCE addr, LDS linear (m173).
// XCD orientation per mode: MODE 2 -> W-panel-resident (mt fast);
// others -> A-slice-resident (nb fast; A slice ~2.4MB fits 4MB L2).
// MODE 0: C=A@W^T+bias (qkv)   MODE 1: +resid (out proj)
// MODE 2: tile-list gather, gelu -> split planes (moe e1)
// MODE 3: tile-list contig A, scatter-add to C (moe e2)
// MODE 4: A=im2col(x planes), +pos (patch embed)
// =====================================================================
template<int MODE>
__global__ __launch_bounds__(256, 4) void gemm_split(
    const u16* __restrict__ Ahp, const u16* __restrict__ Alp,
    const u16* __restrict__ Whp, const u16* __restrict__ Wlp,
    const float* __restrict__ bias, const float* __restrict__ resid,
    float* __restrict__ C, const float* __restrict__ pos,
    u16* __restrict__ Chi, u16* __restrict__ Clo,
    const int* __restrict__ toks, const int* __restrict__ cnts,
    const int* __restrict__ offs, const int* __restrict__ tiles,
    int M, int N, int K)
{
  const int tid = threadIdx.x;
  const int NB = N >> 7;
  const int nm = gridDim.x / NB;
  const int lg = xcd_map(blockIdx.x, gridDim.x);
  int mt, nb;
  if (MODE == 2){ mt = lg % nm; nb = lg / nm; }      // W-panel resident
  else          { nb = lg % NB; mt = lg / NB; }      // A-slice resident

  int cnt = M, base = 0, m0;
  if (MODE == 2 || MODE == 3){
    if (mt >= tiles[0]) return;
    const int e = tiles[1 + 2*mt];
    m0 = tiles[2 + 2*mt];
    cnt  = cnts[e];
    base = offs[e];
    Whp  += (size_t)e * N * K;
    Wlp  += (size_t)e * N * K;
    bias += (size_t)e * N;
  } else {
    m0 = mt * 128;
  }
  const int n0 = nb * 128;

  __shared__ __align__(16) u16 lds[4][4096];   // 32 KB, single buffer

  const int lane = tid & 63, wid = tid >> 6;
  // staging geometry: wave covers rows [wid*32, wid*32+31] of each plane tile
  const int i0 = wid*128 + lane;          // phys chunk (q=0)
  const int r0 = i0 >> 2, r1 = r0 + 16;   // rows
  const int x0 = (i0 & 3) ^ ((r0 >> 1) & 3);
  const int x1 = (i0 & 3) ^ ((r1 >> 1) & 3);
  const int d0 = wid*1024, d1 = wid*1024 + 512;   // u16 LDS dest offsets

  size_t aA0 = 0, aA1 = 0, pb0 = 0, pb1 = 0;
  {
    const int gm0 = m0 + r0, gm1 = m0 + r1;
    if (MODE == 0 || MODE == 1){
      aA0 = (size_t)(gm0 < M ? gm0 : 0) * K + x0*8;
      aA1 = (size_t)(gm1 < M ? gm1 : 0) * K + x1*8;
    }
    if (MODE == 2){
      aA0 = (size_t)(gm0 < cnt ? toks[base+gm0] : 0) * K + x0*8;
      aA1 = (size_t)(gm1 < cnt ? toks[base+gm1] : 0) * K + x1*8;
    }
    if (MODE == 3){
      aA0 = (size_t)(gm0 < cnt ? base+gm0 : 0) * K + x0*8;
      aA1 = (size_t)(gm1 < cnt ? base+gm1 : 0) * K + x1*8;
    }
    if (MODE == 4){
      int b_ = gm0 / 196, pp = gm0 - b_*196;
      pb0 = (size_t)b_*150528 + (size_t)(pp/14)*3584 + (size_t)(pp%14)*16;
      b_ = gm1 / 196; pp = gm1 - b_*196;
      pb1 = (size_t)b_*150528 + (size_t)(pp/14)*3584 + (size_t)(pp%14)*16;
    }
  }
  const size_t aW0 = (size_t)(n0 + r0) * K + x0*8;
  const size_t aW1 = (size_t)(n0 + r1) * K + x1*8;

  auto STAGE = [&](int t){
    const int k0 = t * 32;
    if (MODE == 4){
      const int kq0 = k0 + x0*8, kq1 = k0 + x1*8;
      size_t a0 = pb0 + (size_t)(kq0>>8)*50176 + (size_t)((kq0>>4)&15)*224 + (size_t)(kq0&15);
      size_t a1 = pb1 + (size_t)(kq1>>8)*50176 + (size_t)((kq1>>4)&15)*224 + (size_t)(kq1&15);
      gld16(Ahp + a0, &lds[0][d0]); gld16(Ahp + a1, &lds[0][d1]);
      gld16(Alp + a0, &lds[1][d0]); gld16(Alp + a1, &lds[1][d1]);
    } else {
      gld16(Ahp + aA0 + k0, &lds[0][d0]); gld16(Ahp + aA1 + k0, &lds[0][d1]);
      gld16(Alp + aA0 + k0, &lds[1][d0]); gld16(Alp + aA1 + k0, &lds[1][d1]);
    }
    gld16(Whp + aW0 + k0, &lds[2][d0]); gld16(Whp + aW1 + k0, &lds[2][d1]);
    gld16(Wlp + aW0 + k0, &lds[3][d0]); gld16(Wlp + aW1 + k0, &lds[3][d1]);
  };

  // fragment read offsets (u16 units within a plane)
  const int wr = wid >> 1, wc = wid & 1;
  const int lr = lane & 15, lq = lane >> 4;
  int cA[4], cW[4];
  #pragma unroll
  for (int mi = 0; mi < 4; mi++){
    int ra = wr*64 + mi*16 + lr;
    cA[mi] = (4*ra + (lq ^ ((ra>>1)&3))) * 8;
  }
  #pragma unroll
  for (int nj = 0; nj < 4; nj++){
    int rw = wc*64 + nj*16 + lr;
    cW[nj] = (4*rw + (lq ^ ((rw>>1)&3))) * 8;
  }

  const int NT = K >> 5;
  f32x4 acc[4][4] = {};

  for (int t = 0; t < NT; t++){
    if (t) __syncthreads();        // all reads of the buffer done
    STAGE(t);
    __syncthreads();               // drains vmcnt -> data visible to all waves
    const u16* L = &lds[0][0];
    bf16x8 afh[4], afl[4], bfh[4], bfl[4];
    #pragma unroll
    for (int mi = 0; mi < 4; mi++){
      afh[mi] = *reinterpret_cast<const bf16x8*>(L + cA[mi]);
      afl[mi] = *reinterpret_cast<const bf16x8*>(L + 4096 + cA[mi]);
    }
    #pragma unroll
    for (int nj = 0; nj < 4; nj++){
      bfh[nj] = *reinterpret_cast<const bf16x8*>(L + 2*4096 + cW[nj]);
      bfl[nj] = *reinterpret_cast<const bf16x8*>(L + 3*4096 + cW[nj]);
    }
    #pragma unroll
    for (int mi = 0; mi < 4; mi++)
      #pragma unroll
      for (int nj = 0; nj < 4; nj++){
        acc[mi][nj] = __builtin_amdgcn_mfma_f32_16x16x32_bf16(afh[mi], bfh[nj], acc[mi][nj], 0, 0, 0);
        acc[mi][nj] = __builtin_amdgcn_mfma_f32_16x16x32_bf16(afh[mi], bfl[nj], acc[mi][nj], 0, 0, 0);
        acc[mi][nj] = __builtin_amdgcn_mfma_f32_16x16x32_bf16(afl[mi], bfh[nj], acc[mi][nj], 0, 0, 0);
      }
  }

  // ---- epilogue: C/D layout col=lane&15, row=(lane>>4)*4+reg ----
  #pragma unroll
  for (int nj = 0; nj < 4; nj++){
    const int ncol = n0 + wc*64 + nj*16 + lr;
    const float bv = bias[ncol];
    #pragma unroll
    for (int mi = 0; mi < 4; mi++){
      const int mb = m0 + wr*64 + mi*16 + lq*4;
      #pragma unroll
      for (int j = 0; j < 4; j++){
        const int m = mb + j;
        float v = acc[mi][nj][j] + bv;
        if (MODE == 0){
          if (m < M) C[(size_t)m * N + ncol] = v;
        }
        if (MODE == 1){
          if (m < M) C[(size_t)m * N + ncol] = v + resid[(size_t)m * N + ncol];
        }
        if (MODE == 2){
          if (m < cnt){
            v = 0.5f * v * (1.f + erff(v * 0.70710678118f));
            u16 h, l; split_bf(v, h, l);
            Chi[(size_t)(base + m) * N + ncol] = h;
            Clo[(size_t)(base + m) * N + ncol] = l;
          }
        }
        if (MODE == 3){
          if (m < cnt){
            int tok = toks[base + m];
            C[(size_t)tok * N + ncol] += v;
          }
        }
        if (MODE == 4){
          int b_ = m / 196, pp = m - b_ * 196;
          C[((size_t)b_ * 197 + 1 + pp) * D_MODEL + ncol] =
              v + pos[(size_t)(1 + pp) * D_MODEL + ncol];
        }
      }
    }
  }
}

// ---------------- cls token init ----------------
__global__ __launch_bounds__(256) void cls_init(const float* __restrict__ cls_tk,
                                                const float* __restrict__ pos,
                                                float* __restrict__ xt){
  const int b = blockIdx.x, tid = threadIdx.x;
  for (int d = tid; d < D_MODEL; d += 256)
    xt[((size_t)b*SEQ)*D_MODEL + d] = cls_tk[d] + pos[d];
}

// ---------------- LayerNorm (emits f32 + split planes) ----------------
__global__ __launch_bounds__(256) void ln_kernel(const float* __restrict__ x, size_t xstride,
                                                 const float* __restrict__ w,
                                                 const float* __restrict__ b,
                                                 float* __restrict__ y, size_t ystride,
                                                 u16* __restrict__ yh, u16* __restrict__ yl){
  const int t = blockIdx.x;
  const int tid = threadIdx.x;
  const float* row = x + (size_t)t*xstride;
  float v0 = row[tid], v1 = row[tid+256], v2 = row[tid+512];
  __shared__ float red[4];
  float s = wred_sum(v0+v1+v2);
  if ((tid & 63) == 0) red[tid>>6] = s;
  __syncthreads();
  const float mean = (red[0]+red[1]+red[2]+red[3]) * (1.f/768.f);
  const float d0 = v0-mean, d1 = v1-mean, d2 = v2-mean;
  __syncthreads();
  float q = wred_sum(d0*d0 + d1*d1 + d2*d2);
  if ((tid & 63) == 0) red[tid>>6] = q;
  __syncthreads();
  const float var = (red[0]+red[1]+red[2]+red[3]) * (1.f/768.f);
  const float inv = rsqrtf(var + 1e-5f);
  float o0 = d0*inv*w[tid]     + b[tid];
  float o1 = d1*inv*w[tid+256] + b[tid+256];
  float o2 = d2*inv*w[tid+512] + b[tid+512];
  float* yr = y + (size_t)t*ystride;
  yr[tid] = o0; yr[tid+256] = o1; yr[tid+512] = o2;
  if (yh){
    u16 h, l;
    size_t rb = (size_t)t*768;
    split_bf(o0, h, l); yh[rb+tid]     = h; yl[rb+tid]     = l;
    split_bf(o1, h, l); yh[rb+tid+256] = h; yl[rb+tid+256] = l;
    split_bf(o2, h, l); yh[rb+tid+512] = h; yl[rb+tid+512] = l;
  }
}

// =====================================================================
// fp32 flash-style attention; epilogue emits ctx split planes
// =====================================================================
__global__ __launch_bounds__(256, 3) void attn_f32(const float* __restrict__ qkv,
                                                   u16* __restrict__ ctxh,
                                                   u16* __restrict__ ctxl){
  const int qt = blockIdx.x, h = blockIdx.y, b = blockIdx.z;
  const int tid = threadIdx.x;
  const int tx = tid & 15, ty = tid >> 4;
  __shared__ float Qs[64][65];
  __shared__ float KPs[64][65];
  __shared__ float Vs[64][65];
  const size_t rs = 3*D_MODEL;
  const float* base = qkv + (size_t)b*SEQ*rs + (size_t)h*HDIM;

  #pragma unroll
  for (int it = 0; it < 16; it++){
    int idx = tid + it*256;
    int r = idx >> 6, c = idx & 63;
    int gq = qt*64 + r;
    float v = (gq < SEQ) ? base[(size_t)gq*rs + c] : 0.f;
    Qs[r][c] = v * 0.125f;
  }
  float m_run[4], l_run[4], o[4][4];
  #pragma unroll
  for (int i = 0; i < 4; i++){
    m_run[i] = -3.0e38f; l_run[i] = 0.f;
    #pragma unroll
    for (int j = 0; j < 4; j++) o[i][j] = 0.f;
  }
  __syncthreads();

  for (int kt = 0; kt < 4; kt++){
    #pragma unroll
    for (int it = 0; it < 16; it++){
      int idx = tid + it*256;
      int r = idx >> 6, c = idx & 63;
      int gk = kt*64 + r;
      float kv = (gk < SEQ) ? base[(size_t)gk*rs + D_MODEL   + c] : 0.f;
      float vv = (gk < SEQ) ? base[(size_t)gk*rs + 2*D_MODEL + c] : 0.f;
      KPs[r][c] = kv;
      Vs[r][c]  = vv;
    }
    __syncthreads();
    float s[4][4] = {};
    for (int d = 0; d < 64; d++){
      float qv[4], kv2[4];
      #pragma unroll
      for (int i = 0; i < 4; i++) qv[i]  = Qs[ty*4+i][d];
      #pragma unroll
      for (int j = 0; j < 4; j++) kv2[j] = KPs[tx*4+j][d];
      #pragma unroll
      for (int i = 0; i < 4; i++)
        #pragma unroll
        for (int j = 0; j < 4; j++) s[i][j] += qv[i]*kv2[j];
    }
    #pragma unroll
    for (int j = 0; j < 4; j++){
      if (kt*64 + tx*4 + j >= SEQ){
        #pragma unroll
        for (int i = 0; i < 4; i++) s[i][j] = -3.0e38f;
      }
    }
    float scale[4];
    #pragma unroll
    for (int i = 0; i < 4; i++){
      float mt = fmaxf(fmaxf(s[i][0], s[i][1]), fmaxf(s[i][2], s[i][3]));
      #pragma unroll
      for (int msk = 1; msk <= 8; msk <<= 1) mt = fmaxf(mt, __shfl_xor(mt, msk));
      float mnew = fmaxf(m_run[i], mt);
      scale[i] = __expf(m_run[i] - mnew);
      float ls = 0.f;
      #pragma unroll
      for (int j = 0; j < 4; j++){ s[i][j] = __expf(s[i][j] - mnew); ls += s[i][j]; }
      #pragma unroll
      for (int msk = 1; msk <= 8; msk <<= 1) ls += __shfl_xor(ls, msk);
      l_run[i] = l_run[i]*scale[i] + ls;
      m_run[i] = mnew;
    }
    __syncthreads();
    #pragma unroll
    for (int i = 0; i < 4; i++)
      #pragma unroll
      for (int j = 0; j < 4; j++) KPs[ty*4+i][tx*4+j] = s[i][j];
    __syncthreads();
    #pragma unroll
    for (int i = 0; i < 4; i++)
      #pragma unroll
      for (int j = 0; j < 4; j++) o[i][j] *= scale[i];
    for (int k = 0; k < 64; k++){
      float pv[4], vv[4];
      #pragma unroll
      for (int i = 0; i < 4; i++) pv[i] = KPs[ty*4+i][k];
      #pragma unroll
      for (int j = 0; j < 4; j++) vv[j] = Vs[k][tx*4+j];
      #pragma unroll
      for (int i = 0; i < 4; i++)
        #pragma unroll
        for (int j = 0; j < 4; j++) o[i][j] += pv[i]*vv[j];
    }
    __syncthreads();
  }
  #pragma unroll
  for (int i = 0; i < 4; i++){
    int q = qt*64 + ty*4 + i;
    if (q < SEQ){
      float inv = 1.f / l_run[i];
      #pragma unroll
      for (int j = 0; j < 4; j++){
        u16 hh, ll;
        split_bf(o[i][j]*inv, hh, ll);
        size_t idx = ((size_t)(b*SEQ + q))*D_MODEL + h*HDIM + tx*4 + j;
        ctxh[idx] = hh; ctxl[idx] = ll;
      }
    }
  }
}

// ---------------- gating + routing (count fused) ----------------
__global__ __launch_bounds__(256) void gate_kernel(const float* __restrict__ y,
                                                   const float* __restrict__ gw,
                                                   const float* __restrict__ gb,
                                                   int* __restrict__ eidx,
                                                   int* __restrict__ counts){
  const int t = blockIdx.x;
  const int tid = threadIdx.x;
  const int e = tid >> 6, lane = tid & 63;
  const float* row = y + (size_t)t*D_MODEL;
  const float* wrow = gw + (size_t)e*D_MODEL;
  float acc = 0.f;
  for (int k = lane; k < D_MODEL; k += 64) acc += row[k]*wrow[k];
  acc = wred_sum(acc);
  __shared__ float sc[NEXP];
  if (lane == 0) sc[e] = acc + gb[e];
  __syncthreads();
  if (tid == 0){
    int best = 0; float bv = sc[0];
    #pragma unroll
    for (int k = 1; k < NEXP; k++) if (sc[k] > bv){ bv = sc[k]; best = k; }
    eidx[t] = best;
    atomicAdd(&counts[best], 1);
  }
}

__global__ void zero_counts(int* c){ if (threadIdx.x < 3*NEXP) c[threadIdx.x] = 0; }

__global__ void offsets_kernel(const int* counts, int* offs, int* cursor, int* tiles){
  if (threadIdx.x == 0){
    int o = 0, n = 0;
    for (int e = 0; e < NEXP; e++){
      offs[e] = o; cursor[e] = o;
      for (int m0 = 0; m0 < counts[e]; m0 += 128){
        tiles[1+2*n] = e; tiles[2+2*n] = m0; n++;
      }
      o += counts[e];
    }
    tiles[0] = n;
  }
}

__global__ __launch_bounds__(256) void scatter_kernel(const int* __restrict__ eidx,
                                                      int* cursor, int* __restrict__ toks){
  int i = blockIdx.x*256 + threadIdx.x;
  if (i < NTOK){ int pos = atomicAdd(&cursor[eidx[i]], 1); toks[pos] = i; }
}

// ---------------- fp32 GEMM kept for the head ----------------
__global__ __launch_bounds__(256) void gemm_f32(const float* __restrict__ A,
                                                const float* __restrict__ W,
                                                const float* __restrict__ bias,
                                                const float* __restrict__ resid,
                                                float* __restrict__ C,
                                                int M, int N, int K){
  const int m0 = blockIdx.x*64, bn = blockIdx.y*64;
  const int tid = threadIdx.x;
  const int tx = tid & 15, ty = tid >> 4;
  __shared__ float As[16][65];
  __shared__ float Ws[16][65];
  float acc[4][4] = {};
  for (int k0 = 0; k0 < K; k0 += 16){
    #pragma unroll
    for (int i = 0; i < 4; i++){
      int idx = tid + i*256;
      int k = idx & 15, m = idx >> 4;
      As[k][m] = (m0+m < M) ? A[(size_t)(m0+m)*K + k0 + k] : 0.f;
      Ws[k][m] = (bn+m < N) ? W[(size_t)(bn+m)*K + k0 + k] : 0.f;
    }
    __syncthreads();
    #pragma unroll
    for (int kk = 0; kk < 16; kk++){
      float a0 = As[kk][ty*4+0], a1 = As[kk][ty*4+1], a2 = As[kk][ty*4+2], a3 = As[kk][ty*4+3];
      float w0 = Ws[kk][tx*4+0], w1 = Ws[kk][tx*4+1], w2 = Ws[kk][tx*4+2], w3 = Ws[kk][tx*4+3];
      acc[0][0] += a0*w0; acc[0][1] += a0*w1; acc[0][2] += a0*w2; acc[0][3] += a0*w3;
      acc[1][0] += a1*w0; acc[1][1] += a1*w1; acc[1][2] += a1*w2; acc[1][3] += a1*w3;
      acc[2][0] += a2*w0; acc[2][1] += a2*w1; acc[2][2] += a2*w2; acc[2][3] += a2*w3;
      acc[3][0] += a3*w0; acc[3][1] += a3*w1; acc[3][2] += a3*w2; acc[3][3] += a3*w3;
    }
    __syncthreads();
  }
  #pragma unroll
  for (int i = 0; i < 4; i++){
    int m = m0 + ty*4 + i;
    if (m >= M) continue;
    #pragma unroll
    for (int j = 0; j < 4; j++){
      int n = bn + tx*4 + j;
      if (n >= N) continue;
      float v = acc[i][j];
      if (bias)  v += bias[n];
      if (resid) v += resid[(size_t)m*N + n];
      C[(size_t)m*N + n] = v;
    }
  }
}

// ---------------- launch ----------------
extern "C" void kernel_launch(void* const* d_in, const int* in_sizes, int n_in,
                              void* d_out, int out_size, void* d_ws, size_t ws_size,
                              hipStream_t stream){
  const float* x      = (const float*)d_in[0];
  const float* conv_w = (const float*)d_in[1];
  const float* conv_b = (const float*)d_in[2];
  const float* cls_tk = (const float*)d_in[3];
  const float* pos    = (const float*)d_in[4];
  const float* ln1w   = (const float*)d_in[5];
  const float* ln1b   = (const float*)d_in[6];
  const float* qkvw   = (const float*)d_in[7];
  const float* qkvb   = (const float*)d_in[8];
  const float* outw   = (const float*)d_in[9];
  const float* outb   = (const float*)d_in[10];
  const float* ln2w   = (const float*)d_in[11];
  const float* ln2b   = (const float*)d_in[12];
  const float* gatew  = (const float*)d_in[13];
  const float* gateb  = (const float*)d_in[14];
  const float* e1w    = (const float*)d_in[15];
  const float* e1b    = (const float*)d_in[16];
  const float* e2w    = (const float*)d_in[17];
  const float* e2b    = (const float*)d_in[18];
  const float* fnw    = (const float*)d_in[19];
  const float* fnb    = (const float*)d_in[20];
  const float* headw  = (const float*)d_in[21];
  const float* headb  = (const float*)d_in[22];
  float* out = (float*)d_out;

  // ---- workspace carve (f32 region, then u16 planes; all 16B-aligned) ----
  float* ws    = (float*)d_ws;
  float* xt    = ws;                               // 6304*768
  float* y     = xt  + (size_t)NTOK*D_MODEL;
  float* qkv   = y   + (size_t)NTOK*D_MODEL;       // 6304*2304
  float* clsln = qkv + (size_t)NTOK*3*D_MODEL;     // 32*768
  int*   eidx   = (int*)(clsln + (size_t)BATCH*D_MODEL);
  int*   toks   = eidx + NTOK;
  int*   counts = toks + NTOK;
  int*   offs   = counts + NEXP;
  int*   cursor = offs + NEXP;
  int*   tiles  = cursor + NEXP;                   // 1+2*56
  u16* up = (u16*)(((size_t)(tiles + 120) + 15) & ~(size_t)15);
  const size_t nY  = (size_t)NTOK*D_MODEL;
  const size_t nH1 = (size_t)NTOK*HID_N;
  const size_t nX  = (size_t)BATCH*3*224*224;
  const size_t nCW = 768*768;
  const size_t nQW = (size_t)DEPTH_N*3*D_MODEL*D_MODEL;
  const size_t nOW = (size_t)DEPTH_N*D_MODEL*D_MODEL;
  const size_t nE1 = (size_t)DEPTH_N*NEXP*HID_N*D_MODEL;
  const size_t nE2 = (size_t)DEPTH_N*NEXP*D_MODEL*HID_N;
  u16 *yh = up,      *yl = yh + nY;
  u16 *ch = yl + nY, *cl = ch + nY;                // ctx planes
  u16 *h1h = cl + nY, *h1l = h1h + nH1;
  u16 *xh = h1l + nH1, *xl = xh + nX;
  u16 *cwh = xl + nX,  *cwl = cwh + nCW;
  u16 *qwh = cwl + nCW, *qwl = qwh + nQW;
  u16 *owh = qwl + nQW, *owl = owh + nOW;
  u16 *e1h = owl + nOW, *e1l = e1h + nE1;
  u16 *e2h = e1l + nE1, *e2l = e2h + nE2;

  dim3 b256(256);

  // ---- one-time (per launch) weight/x split conversions ----
  split_many<<<2048, b256, 0, stream>>>(x,      xh,  xl,  (long)(nX/4));
  split_many<<<2048, b256, 0, stream>>>(conv_w, cwh, cwl, (long)(nCW/4));
  split_many<<<2048, b256, 0, stream>>>(qkvw,   qwh, qwl, (long)(nQW/4));
  split_many<<<2048, b256, 0, stream>>>(outw,   owh, owl, (long)(nOW/4));
  split_many<<<2048, b256, 0, stream>>>(e1w,    e1h, e1l, (long)(nE1/4));
  split_many<<<2048, b256, 0, stream>>>(e2w,    e2h, e2l, (long)(nE2/4));

  gemm_split<4><<<dim3(49*6), b256, 0, stream>>>(xh, xl, cwh, cwl,
      conv_b, nullptr, xt, pos, nullptr, nullptr,
      nullptr, nullptr, nullptr, nullptr, 6272, D_MODEL, 768);
  cls_init<<<dim3(BATCH), b256, 0, stream>>>(cls_tk, pos, xt);

  for (int i = 0; i < DEPTH_N; i++){
    ln_kernel<<<dim3(NTOK), b256, 0, stream>>>(xt, D_MODEL,
        ln1w + (size_t)i*D_MODEL, ln1b + (size_t)i*D_MODEL, y, D_MODEL, yh, yl);
    gemm_split<0><<<dim3(50*18), b256, 0, stream>>>(yh, yl,
        qwh + (size_t)i*3*D_MODEL*D_MODEL, qwl + (size_t)i*3*D_MODEL*D_MODEL,
        qkvb + (size_t)i*3*D_MODEL, nullptr, qkv, nullptr, nullptr, nullptr,
        nullptr, nullptr, nullptr, nullptr, NTOK, 3*D_MODEL, D_MODEL);
    attn_f32<<<dim3(4, NHEAD, BATCH), b256, 0, stream>>>(qkv, ch, cl);
    gemm_split<1><<<dim3(50*6), b256, 0, stream>>>(ch, cl,
        owh + (size_t)i*D_MODEL*D_MODEL, owl + (size_t)i*D_MODEL*D_MODEL,
        outb + (size_t)i*D_MODEL, xt, xt, nullptr, nullptr, nullptr,
        nullptr, nullptr, nullptr, nullptr, NTOK, D_MODEL, D_MODEL);
    ln_kernel<<<dim3(NTOK), b256, 0, stream>>>(xt, D_MODEL,
        ln2w + (size_t)i*D_MODEL, ln2b + (size_t)i*D_MODEL, y, D_MODEL, yh, yl);
    zero_counts<<<1, 64, 0, stream>>>(counts);
    gate_kernel<<<dim3(NTOK), b256, 0, stream>>>(y,
        gatew + (size_t)i*NEXP*D_MODEL, gateb + (size_t)i*NEXP, eidx, counts);
    offsets_kernel<<<1, 64, 0, stream>>>(counts, offs, cursor, tiles);
    scatter_kernel<<<dim3((NTOK+255)/256), b256, 0, stream>>>(eidx, cursor, toks);
    gemm_split<2><<<dim3(53*(HID_N/128)), b256, 0, stream>>>(yh, yl,
        e1h + (size_t)i*NEXP*HID_N*D_MODEL, e1l + (size_t)i*NEXP*HID_N*D_MODEL,
        e1b + (size_t)i*NEXP*HID_N, nullptr, nullptr, nullptr, h1h, h1l,
        toks, counts, offs, tiles, NTOK, HID_N, D_MODEL);
    gemm_split<3><<<dim3(53*(D_MODEL/128)), b256, 0, stream>>>(h1h, h1l,
        e2h + (size_t)i*NEXP*D_MODEL*HID_N, e2l + (size_t)i*NEXP*D_MODEL*HID_N,
        e2b + (size_t)i*NEXP*D_MODEL, nullptr, xt, nullptr, nullptr, nullptr,
        toks, counts, offs, tiles, NTOK, D_MODEL, HID_N);
  }

  ln_kernel<<<dim3(BATCH), b256, 0, stream>>>(xt, (size_t)SEQ*D_MODEL, fnw, fnb,
      clsln, D_MODEL, nullptr, nullptr);
  gemm_f32<<<dim3(1, 16), b256, 0, stream>>>(clsln, headw, headb, nullptr, out, BATCH, 1000, D_MODEL);
}

// Round 9
// 10618.925 us; speedup vs baseline: 1.0732x; 1.0732x over previous
//
#include <hip/hip_runtime.h>
#include <hip/hip_bf16.h>
#include <math.h>

#define D_MODEL 768
#define SEQ     197
#define BATCH   32
#define NTOK    (BATCH*SEQ)   // 6304
#define NHEAD   12
#define HDIM    64
#define NEXP    4
#define HID_N   3072
#define DEPTH_N 12

typedef __attribute__((ext_vector_type(4))) float f32x4;
typedef __attribute__((ext_vector_type(8))) short bf16x8;
typedef __attribute__((ext_vector_type(4))) unsigned short u16x4;
typedef unsigned short u16;

// fp32 -> bf16 round-to-nearest-even
static __device__ __forceinline__ u16 f2bf(float f){
  unsigned int u = __builtin_bit_cast(unsigned int, f);
  u += 0x7FFFu + ((u >> 16) & 1u);
  return (u16)(u >> 16);
}
// split x ~= hi + lo (bf16 each)
static __device__ __forceinline__ void split_bf(float x, u16& h, u16& l){
  h = f2bf(x);
  float hf = __builtin_bit_cast(float, (unsigned)h << 16);
  l = f2bf(x - hf);
}

static __device__ __forceinline__ float wred_sum(float v){
  #pragma unroll
  for (int off = 32; off; off >>= 1) v += __shfl_down(v, off);
  return v;
}

// global -> LDS direct, 16 B per lane (dest wave-uniform base + lane*16)
static __device__ __forceinline__ void gld16(const u16* g, u16* l){
  __builtin_amdgcn_global_load_lds(
      (const __attribute__((address_space(1))) unsigned int*)g,
      (__attribute__((address_space(3))) unsigned int*)l, 16, 0, 0);
}

// ---------------- split converter (weights, x) ----------------
__global__ __launch_bounds__(256) void split_many(const float* __restrict__ src,
                                                  u16* __restrict__ hi,
                                                  u16* __restrict__ lo, long n4){
  for (long i = blockIdx.x*256L + threadIdx.x; i < n4; i += (long)gridDim.x*256){
    f32x4 v = *reinterpret_cast<const f32x4*>(src + i*4);
    u16x4 h, l;
    #pragma unroll
    for (int j = 0; j < 4; j++){ u16 hh, ll; split_bf(v[j], hh, ll); h[j]=hh; l[j]=ll; }
    *reinterpret_cast<u16x4*>(hi + i*4) = h;
    *reinterpret_cast<u16x4*>(lo + i*4) = l;
  }
}

// =====================================================================
// split-precision MFMA GEMM, plane inputs, global_load_lds staging.
// C = A @ W^T via Ah*Wh + Ah*Wl + Al*Wh (error ~2^-16).
// 128x128 tile, BK=32, 4 waves (2x2), double-buffered LDS (64 KB),
// counted vmcnt(8) pipeline (loads stay in flight across barrier).
//
// XCD traffic shaping: grid = 8 * MTg * NBg. Block b -> xcd = b&7,
// idx = b>>3. XCDs form MG x NG regions (MG = 8/NG): xcd covers
// mt in [mg*MTg,..), nb in [ng*NBg,..). Inner order nb-FAST:
// W-slice (NBg panels, sized <= ~3.5 MB) stays L2-resident for the
// whole dispatch; each A-tile fetched once, reused NBg times.
// MODE 0: C=A@W^T+bias (qkv)   MODE 1: +resid (out proj)
// MODE 2: tile-list gather, gelu -> split planes (moe e1)
// MODE 3: tile-list contig A, scatter-add to C (moe e2)
// MODE 4: A=im2col(x planes), +pos (patch embed)
// =====================================================================
template<int MODE, int NG>
__global__ __launch_bounds__(256, 2) void gemm_split(
    const u16* __restrict__ Ahp, const u16* __restrict__ Alp,
    const u16* __restrict__ Whp, const u16* __restrict__ Wlp,
    const float* __restrict__ bias, const float* __restrict__ resid,
    float* __restrict__ C, const float* __restrict__ pos,
    u16* __restrict__ Chi, u16* __restrict__ Clo,
    const int* __restrict__ toks, const int* __restrict__ cnts,
    const int* __restrict__ offs, const int* __restrict__ tiles,
    int MTg, int NBg, int M, int N, int K)
{
  const int tid = threadIdx.x;
  const int NB = N >> 7;
  const int xcd = blockIdx.x & 7;
  const int idx = blockIdx.x >> 3;
  const int mg = xcd / NG, ng = xcd - mg*NG;
  const int mt = mg*MTg + idx / NBg;
  const int nb = ng*NBg + idx % NBg;
  if (nb >= NB) return;

  int cnt = M, base = 0, m0;
  if (MODE == 2 || MODE == 3){
    if (mt >= tiles[0]) return;
    const int e = tiles[1 + 2*mt];
    m0 = tiles[2 + 2*mt];
    cnt  = cnts[e];
    base = offs[e];
    Whp  += (size_t)e * N * K;
    Wlp  += (size_t)e * N * K;
    bias += (size_t)e * N;
  } else {
    m0 = mt * 128;
    if (m0 >= M) return;
  }
  const int n0 = nb * 128;

  __shared__ __align__(16) u16 lds[2][4][4096];   // 64 KB, double buffer

  const int lane = tid & 63, wid = tid >> 6;
  // staging geometry: wave covers rows [wid*32, wid*32+31] of each plane tile
  const int i0 = wid*128 + lane;          // phys chunk (q=0)
  const int r0 = i0 >> 2, r1 = r0 + 16;   // rows
  const int x0 = (i0 & 3) ^ ((r0 >> 1) & 3);
  const int x1 = (i0 & 3) ^ ((r1 >> 1) & 3);
  const int d0 = wid*1024, d1 = wid*1024 + 512;   // u16 LDS dest offsets

  size_t aA0 = 0, aA1 = 0, pb0 = 0, pb1 = 0;
  {
    const int gm0 = m0 + r0, gm1 = m0 + r1;
    if (MODE == 0 || MODE == 1){
      aA0 = (size_t)(gm0 < M ? gm0 : 0) * K + x0*8;
      aA1 = (size_t)(gm1 < M ? gm1 : 0) * K + x1*8;
    }
    if (MODE == 2){
      aA0 = (size_t)(gm0 < cnt ? toks[base+gm0] : 0) * K + x0*8;
      aA1 = (size_t)(gm1 < cnt ? toks[base+gm1] : 0) * K + x1*8;
    }
    if (MODE == 3){
      aA0 = (size_t)(gm0 < cnt ? base+gm0 : 0) * K + x0*8;
      aA1 = (size_t)(gm1 < cnt ? base+gm1 : 0) * K + x1*8;
    }
    if (MODE == 4){
      int b_ = gm0 / 196, pp = gm0 - b_*196;
      pb0 = (size_t)b_*150528 + (size_t)(pp/14)*3584 + (size_t)(pp%14)*16;
      b_ = gm1 / 196; pp = gm1 - b_*196;
      pb1 = (size_t)b_*150528 + (size_t)(pp/14)*3584 + (size_t)(pp%14)*16;
    }
  }
  const size_t aW0 = (size_t)(n0 + r0) * K + x0*8;
  const size_t aW1 = (size_t)(n0 + r1) * K + x1*8;

  auto STAGE = [&](int buf, int t){
    const int k0 = t * 32;
    if (MODE == 4){
      const int kq0 = k0 + x0*8, kq1 = k0 + x1*8;
      size_t a0 = pb0 + (size_t)(kq0>>8)*50176 + (size_t)((kq0>>4)&15)*224 + (size_t)(kq0&15);
      size_t a1 = pb1 + (size_t)(kq1>>8)*50176 + (size_t)((kq1>>4)&15)*224 + (size_t)(kq1&15);
      gld16(Ahp + a0, &lds[buf][0][d0]); gld16(Ahp + a1, &lds[buf][0][d1]);
      gld16(Alp + a0, &lds[buf][1][d0]); gld16(Alp + a1, &lds[buf][1][d1]);
    } else {
      gld16(Ahp + aA0 + k0, &lds[buf][0][d0]); gld16(Ahp + aA1 + k0, &lds[buf][0][d1]);
      gld16(Alp + aA0 + k0, &lds[buf][1][d0]); gld16(Alp + aA1 + k0, &lds[buf][1][d1]);
    }
    gld16(Whp + aW0 + k0, &lds[buf][2][d0]); gld16(Whp + aW1 + k0, &lds[buf][2][d1]);
    gld16(Wlp + aW0 + k0, &lds[buf][3][d0]); gld16(Wlp + aW1 + k0, &lds[buf][3][d1]);
  };

  // fragment read offsets (u16 units within a plane)
  const int wr = wid >> 1, wc = wid & 1;
  const int lr = lane & 15, lq = lane >> 4;
  int cA[4], cW[4];
  #pragma unroll
  for (int mi = 0; mi < 4; mi++){
    int ra = wr*64 + mi*16 + lr;
    cA[mi] = (4*ra + (lq ^ ((ra>>1)&3))) * 8;
  }
  #pragma unroll
  for (int nj = 0; nj < 4; nj++){
    int rw = wc*64 + nj*16 + lr;
    cW[nj] = (4*rw + (lq ^ ((rw>>1)&3))) * 8;
  }

  const int NT = K >> 5;
  f32x4 acc[4][4] = {};

  STAGE(0, 0);
  for (int t = 0; t < NT; t++){
    const int buf = t & 1;
    if (t + 1 < NT){
      STAGE(buf ^ 1, t + 1);
      asm volatile("s_waitcnt vmcnt(8)" ::: "memory");
    } else {
      asm volatile("s_waitcnt vmcnt(0)" ::: "memory");
    }
    __builtin_amdgcn_s_barrier();
    asm volatile("" ::: "memory");
    const u16* L = &lds[buf][0][0];
    bf16x8 afh[4], afl[4], bfh[4], bfl[4];
    #pragma unroll
    for (int mi = 0; mi < 4; mi++){
      afh[mi] = *reinterpret_cast<const bf16x8*>(L + cA[mi]);
      afl[mi] = *reinterpret_cast<const bf16x8*>(L + 4096 + cA[mi]);
    }
    #pragma unroll
    for (int nj = 0; nj < 4; nj++){
      bfh[nj] = *reinterpret_cast<const bf16x8*>(L + 2*4096 + cW[nj]);
      bfl[nj] = *reinterpret_cast<const bf16x8*>(L + 3*4096 + cW[nj]);
    }
    #pragma unroll
    for (int mi = 0; mi < 4; mi++)
      #pragma unroll
      for (int nj = 0; nj < 4; nj++){
        acc[mi][nj] = __builtin_amdgcn_mfma_f32_16x16x32_bf16(afh[mi], bfh[nj], acc[mi][nj], 0, 0, 0);
        acc[mi][nj] = __builtin_amdgcn_mfma_f32_16x16x32_bf16(afh[mi], bfl[nj], acc[mi][nj], 0, 0, 0);
        acc[mi][nj] = __builtin_amdgcn_mfma_f32_16x16x32_bf16(afl[mi], bfh[nj], acc[mi][nj], 0, 0, 0);
      }
    asm volatile("" ::: "memory");
    __builtin_amdgcn_s_barrier();
  }

  // ---- epilogue: C/D layout col=lane&15, row=(lane>>4)*4+reg ----
  #pragma unroll
  for (int nj = 0; nj < 4; nj++){
    const int ncol = n0 + wc*64 + nj*16 + lr;
    const float bv = bias[ncol];
    #pragma unroll
    for (int mi = 0; mi < 4; mi++){
      const int mb = m0 + wr*64 + mi*16 + lq*4;
      #pragma unroll
      for (int j = 0; j < 4; j++){
        const int m = mb + j;
        float v = acc[mi][nj][j] + bv;
        if (MODE == 0){
          if (m < M) C[(size_t)m * N + ncol] = v;
        }
        if (MODE == 1){
          if (m < M) C[(size_t)m * N + ncol] = v + resid[(size_t)m * N + ncol];
        }
        if (MODE == 2){
          if (m < cnt){
            v = 0.5f * v * (1.f + erff(v * 0.70710678118f));
            u16 h, l; split_bf(v, h, l);
            Chi[(size_t)(base + m) * N + ncol] = h;
            Clo[(size_t)(base + m) * N + ncol] = l;
          }
        }
        if (MODE == 3){
          if (m < cnt){
            int tok = toks[base + m];
            C[(size_t)tok * N + ncol] += v;
          }
        }
        if (MODE == 4){
          int b_ = m / 196, pp = m - b_ * 196;
          C[((size_t)b_ * 197 + 1 + pp) * D_MODEL + ncol] =
              v + pos[(size_t)(1 + pp) * D_MODEL + ncol];
        }
      }
    }
  }
}

// ---------------- cls token init ----------------
__global__ __launch_bounds__(256) void cls_init(const float* __restrict__ cls_tk,
                                                const float* __restrict__ pos,
                                                float* __restrict__ xt){
  const int b = blockIdx.x, tid = threadIdx.x;
  for (int d = tid; d < D_MODEL; d += 256)
    xt[((size_t)b*SEQ)*D_MODEL + d] = cls_tk[d] + pos[d];
}

// ---------------- LayerNorm (emits f32 + split planes) ----------------
__global__ __launch_bounds__(256) void ln_kernel(const float* __restrict__ x, size_t xstride,
                                                 const float* __restrict__ w,
                                                 const float* __restrict__ b,
                                                 float* __restrict__ y, size_t ystride,
                                                 u16* __restrict__ yh, u16* __restrict__ yl){
  const int t = blockIdx.x;
  const int tid = threadIdx.x;
  const float* row = x + (size_t)t*xstride;
  float v0 = row[tid], v1 = row[tid+256], v2 = row[tid+512];
  __shared__ float red[4];
  float s = wred_sum(v0+v1+v2);
  if ((tid & 63) == 0) red[tid>>6] = s;
  __syncthreads();
  const float mean = (red[0]+red[1]+red[2]+red[3]) * (1.f/768.f);
  const float d0 = v0-mean, d1 = v1-mean, d2 = v2-mean;
  __syncthreads();
  float q = wred_sum(d0*d0 + d1*d1 + d2*d2);
  if ((tid & 63) == 0) red[tid>>6] = q;
  __syncthreads();
  const float var = (red[0]+red[1]+red[2]+red[3]) * (1.f/768.f);
  const float inv = rsqrtf(var + 1e-5f);
  float o0 = d0*inv*w[tid]     + b[tid];
  float o1 = d1*inv*w[tid+256] + b[tid+256];
  float o2 = d2*inv*w[tid+512] + b[tid+512];
  float* yr = y + (size_t)t*ystride;
  yr[tid] = o0; yr[tid+256] = o1; yr[tid+512] = o2;
  if (yh){
    u16 h, l;
    size_t rb = (size_t)t*768;
    split_bf(o0, h, l); yh[rb+tid]     = h; yl[rb+tid]     = l;
    split_bf(o1, h, l); yh[rb+tid+256] = h; yl[rb+tid+256] = l;
    split_bf(o2, h, l); yh[rb+tid+512] = h; yl[rb+tid+512] = l;
  }
}

// =====================================================================
// fp32 flash-style attention; epilogue emits ctx split planes
// =====================================================================
__global__ __launch_bounds__(256, 3) void attn_f32(const float* __restrict__ qkv,
                                                   u16* __restrict__ ctxh,
                                                   u16* __restrict__ ctxl){
  const int qt = blockIdx.x, h = blockIdx.y, b = blockIdx.z;
  const int tid = threadIdx.x;
  const int tx = tid & 15, ty = tid >> 4;
  __shared__ float Qs[64][65];
  __shared__ float KPs[64][65];
  __shared__ float Vs[64][65];
  const size_t rs = 3*D_MODEL;
  const float* base = qkv + (size_t)b*SEQ*rs + (size_t)h*HDIM;

  #pragma unroll
  for (int it = 0; it < 16; it++){
    int idx = tid + it*256;
    int r = idx >> 6, c = idx & 63;
    int gq = qt*64 + r;
    float v = (gq < SEQ) ? base[(size_t)gq*rs + c] : 0.f;
    Qs[r][c] = v * 0.125f;
  }
  float m_run[4], l_run[4], o[4][4];
  #pragma unroll
  for (int i = 0; i < 4; i++){
    m_run[i] = -3.0e38f; l_run[i] = 0.f;
    #pragma unroll
    for (int j = 0; j < 4; j++) o[i][j] = 0.f;
  }
  __syncthreads();

  for (int kt = 0; kt < 4; kt++){
    #pragma unroll
    for (int it = 0; it < 16; it++){
      int idx = tid + it*256;
      int r = idx >> 6, c = idx & 63;
      int gk = kt*64 + r;
      float kv = (gk < SEQ) ? base[(size_t)gk*rs + D_MODEL   + c] : 0.f;
      float vv = (gk < SEQ) ? base[(size_t)gk*rs + 2*D_MODEL + c] : 0.f;
      KPs[r][c] = kv;
      Vs[r][c]  = vv;
    }
    __syncthreads();
    float s[4][4] = {};
    for (int d = 0; d < 64; d++){
      float qv[4], kv2[4];
      #pragma unroll
      for (int i = 0; i < 4; i++) qv[i]  = Qs[ty*4+i][d];
      #pragma unroll
      for (int j = 0; j < 4; j++) kv2[j] = KPs[tx*4+j][d];
      #pragma unroll
      for (int i = 0; i < 4; i++)
        #pragma unroll
        for (int j = 0; j < 4; j++) s[i][j] += qv[i]*kv2[j];
    }
    #pragma unroll
    for (int j = 0; j < 4; j++){
      if (kt*64 + tx*4 + j >= SEQ){
        #pragma unroll
        for (int i = 0; i < 4; i++) s[i][j] = -3.0e38f;
      }
    }
    float scale[4];
    #pragma unroll
    for (int i = 0; i < 4; i++){
      float mt = fmaxf(fmaxf(s[i][0], s[i][1]), fmaxf(s[i][2], s[i][3]));
      #pragma unroll
      for (int msk = 1; msk <= 8; msk <<= 1) mt = fmaxf(mt, __shfl_xor(mt, msk));
      float mnew = fmaxf(m_run[i], mt);
      scale[i] = __expf(m_run[i] - mnew);
      float ls = 0.f;
      #pragma unroll
      for (int j = 0; j < 4; j++){ s[i][j] = __expf(s[i][j] - mnew); ls += s[i][j]; }
      #pragma unroll
      for (int msk = 1; msk <= 8; msk <<= 1) ls += __shfl_xor(ls, msk);
      l_run[i] = l_run[i]*scale[i] + ls;
      m_run[i] = mnew;
    }
    __syncthreads();
    #pragma unroll
    for (int i = 0; i < 4; i++)
      #pragma unroll
      for (int j = 0; j < 4; j++) KPs[ty*4+i][tx*4+j] = s[i][j];
    __syncthreads();
    #pragma unroll
    for (int i = 0; i < 4; i++)
      #pragma unroll
      for (int j = 0; j < 4; j++) o[i][j] *= scale[i];
    for (int k = 0; k < 64; k++){
      float pv[4], vv[4];
      #pragma unroll
      for (int i = 0; i < 4; i++) pv[i] = KPs[ty*4+i][k];
      #pragma unroll
      for (int j = 0; j < 4; j++) vv[j] = Vs[k][tx*4+j];
      #pragma unroll
      for (int i = 0; i < 4; i++)
        #pragma unroll
        for (int j = 0; j < 4; j++) o[i][j] += pv[i]*vv[j];
    }
    __syncthreads();
  }
  #pragma unroll
  for (int i = 0; i < 4; i++){
    int q = qt*64 + ty*4 + i;
    if (q < SEQ){
      float inv = 1.f / l_run[i];
      #pragma unroll
      for (int j = 0; j < 4; j++){
        u16 hh, ll;
        split_bf(o[i][j]*inv, hh, ll);
        size_t idx = ((size_t)(b*SEQ + q))*D_MODEL + h*HDIM + tx*4 + j;
        ctxh[idx] = hh; ctxl[idx] = ll;
      }
    }
  }
}

// ---------------- gating + routing (count fused) ----------------
__global__ __launch_bounds__(256) void gate_kernel(const float* __restrict__ y,
                                                   const float* __restrict__ gw,
                                                   const float* __restrict__ gb,
                                                   int* __restrict__ eidx,
                                                   int* __restrict__ counts){
  const int t = blockIdx.x;
  const int tid = threadIdx.x;
  const int e = tid >> 6, lane = tid & 63;
  const float* row = y + (size_t)t*D_MODEL;
  const float* wrow = gw + (size_t)e*D_MODEL;
  float acc = 0.f;
  for (int k = lane; k < D_MODEL; k += 64) acc += row[k]*wrow[k];
  acc = wred_sum(acc);
  __shared__ float sc[NEXP];
  if (lane == 0) sc[e] = acc + gb[e];
  __syncthreads();
  if (tid == 0){
    int best = 0; float bv = sc[0];
    #pragma unroll
    for (int k = 1; k < NEXP; k++) if (sc[k] > bv){ bv = sc[k]; best = k; }
    eidx[t] = best;
    atomicAdd(&counts[best], 1);
  }
}

__global__ void zero_counts(int* c){ if (threadIdx.x < 3*NEXP) c[threadIdx.x] = 0; }

__global__ void offsets_kernel(const int* counts, int* offs, int* cursor, int* tiles){
  if (threadIdx.x == 0){
    int o = 0, n = 0;
    for (int e = 0; e < NEXP; e++){
      offs[e] = o; cursor[e] = o;
      for (int m0 = 0; m0 < counts[e]; m0 += 128){
        tiles[1+2*n] = e; tiles[2+2*n] = m0; n++;
      }
      o += counts[e];
    }
    tiles[0] = n;
  }
}

__global__ __launch_bounds__(256) void scatter_kernel(const int* __restrict__ eidx,
                                                      int* cursor, int* __restrict__ toks){
  int i = blockIdx.x*256 + threadIdx.x;
  if (i < NTOK){ int pos = atomicAdd(&cursor[eidx[i]], 1); toks[pos] = i; }
}

// ---------------- fp32 GEMM kept for the head ----------------
__global__ __launch_bounds__(256) void gemm_f32(const float* __restrict__ A,
                                                const float* __restrict__ W,
                                                const float* __restrict__ bias,
                                                const float* __restrict__ resid,
                                                float* __restrict__ C,
                                                int M, int N, int K){
  const int m0 = blockIdx.x*64, bn = blockIdx.y*64;
  const int tid = threadIdx.x;
  const int tx = tid & 15, ty = tid >> 4;
  __shared__ float As[16][65];
  __shared__ float Ws[16][65];
  float acc[4][4] = {};
  for (int k0 = 0; k0 < K; k0 += 16){
    #pragma unroll
    for (int i = 0; i < 4; i++){
      int idx = tid + i*256;
      int k = idx & 15, m = idx >> 4;
      As[k][m] = (m0+m < M) ? A[(size_t)(m0+m)*K + k0 + k] : 0.f;
      Ws[k][m] = (bn+m < N) ? W[(size_t)(bn+m)*K + k0 + k] : 0.f;
    }
    __syncthreads();
    #pragma unroll
    for (int kk = 0; kk < 16; kk++){
      float a0 = As[kk][ty*4+0], a1 = As[kk][ty*4+1], a2 = As[kk][ty*4+2], a3 = As[kk][ty*4+3];
      float w0 = Ws[kk][tx*4+0], w1 = Ws[kk][tx*4+1], w2 = Ws[kk][tx*4+2], w3 = Ws[kk][tx*4+3];
      acc[0][0] += a0*w0; acc[0][1] += a0*w1; acc[0][2] += a0*w2; acc[0][3] += a0*w3;
      acc[1][0] += a1*w0; acc[1][1] += a1*w1; acc[1][2] += a1*w2; acc[1][3] += a1*w3;
      acc[2][0] += a2*w0; acc[2][1] += a2*w1; acc[2][2] += a2*w2; acc[2][3] += a2*w3;
      acc[3][0] += a3*w0; acc[3][1] += a3*w1; acc[3][2] += a3*w2; acc[3][3] += a3*w3;
    }
    __syncthreads();
  }
  #pragma unroll
  for (int i = 0; i < 4; i++){
    int m = m0 + ty*4 + i;
    if (m >= M) continue;
    #pragma unroll
    for (int j = 0; j < 4; j++){
      int n = bn + tx*4 + j;
      if (n >= N) continue;
      float v = acc[i][j];
      if (bias)  v += bias[n];
      if (resid) v += resid[(size_t)m*N + n];
      C[(size_t)m*N + n] = v;
    }
  }
}

// ---------------- launch ----------------
extern "C" void kernel_launch(void* const* d_in, const int* in_sizes, int n_in,
                              void* d_out, int out_size, void* d_ws, size_t ws_size,
                              hipStream_t stream){
  const float* x      = (const float*)d_in[0];
  const float* conv_w = (const float*)d_in[1];
  const float* conv_b = (const float*)d_in[2];
  const float* cls_tk = (const float*)d_in[3];
  const float* pos    = (const float*)d_in[4];
  const float* ln1w   = (const float*)d_in[5];
  const float* ln1b   = (const float*)d_in[6];
  const float* qkvw   = (const float*)d_in[7];
  const float* qkvb   = (const float*)d_in[8];
  const float* outw   = (const float*)d_in[9];
  const float* outb   = (const float*)d_in[10];
  const float* ln2w   = (const float*)d_in[11];
  const float* ln2b   = (const float*)d_in[12];
  const float* gatew  = (const float*)d_in[13];
  const float* gateb  = (const float*)d_in[14];
  const float* e1w    = (const float*)d_in[15];
  const float* e1b    = (const float*)d_in[16];
  const float* e2w    = (const float*)d_in[17];
  const float* e2b    = (const float*)d_in[18];
  const float* fnw    = (const float*)d_in[19];
  const float* fnb    = (const float*)d_in[20];
  const float* headw  = (const float*)d_in[21];
  const float* headb  = (const float*)d_in[22];
  float* out = (float*)d_out;

  // ---- workspace carve (f32 region, then u16 planes; all 16B-aligned) ----
  float* ws    = (float*)d_ws;
  float* xt    = ws;                               // 6304*768
  float* y     = xt  + (size_t)NTOK*D_MODEL;
  float* qkv   = y   + (size_t)NTOK*D_MODEL;       // 6304*2304
  float* clsln = qkv + (size_t)NTOK*3*D_MODEL;     // 32*768
  int*   eidx   = (int*)(clsln + (size_t)BATCH*D_MODEL);
  int*   toks   = eidx + NTOK;
  int*   counts = toks + NTOK;
  int*   offs   = counts + NEXP;
  int*   cursor = offs + NEXP;
  int*   tiles  = cursor + NEXP;                   // 1+2*56
  u16* up = (u16*)(((size_t)(tiles + 120) + 15) & ~(size_t)15);
  const size_t nY  = (size_t)NTOK*D_MODEL;
  const size_t nH1 = (size_t)NTOK*HID_N;
  const size_t nX  = (size_t)BATCH*3*224*224;
  const size_t nCW = 768*768;
  const size_t nQW = (size_t)DEPTH_N*3*D_MODEL*D_MODEL;
  const size_t nOW = (size_t)DEPTH_N*D_MODEL*D_MODEL;
  const size_t nE1 = (size_t)DEPTH_N*NEXP*HID_N*D_MODEL;
  const size_t nE2 = (size_t)DEPTH_N*NEXP*D_MODEL*HID_N;
  u16 *yh = up,      *yl = yh + nY;
  u16 *ch = yl + nY, *cl = ch + nY;                // ctx planes
  u16 *h1h = cl + nY, *h1l = h1h + nH1;
  u16 *xh = h1l + nH1, *xl = xh + nX;
  u16 *cwh = xl + nX,  *cwl = cwh + nCW;
  u16 *qwh = cwl + nCW, *qwl = qwh + nQW;
  u16 *owh = qwl + nQW, *owl = owh + nOW;
  u16 *e1h = owl + nOW, *e1l = e1h + nE1;
  u16 *e2h = e1l + nE1, *e2l = e2h + nE2;

  dim3 b256(256);

  // ---- one-time (per launch) weight/x split conversions ----
  split_many<<<2048, b256, 0, stream>>>(x,      xh,  xl,  (long)(nX/4));
  split_many<<<2048, b256, 0, stream>>>(conv_w, cwh, cwl, (long)(nCW/4));
  split_many<<<2048, b256, 0, stream>>>(qkvw,   qwh, qwl, (long)(nQW/4));
  split_many<<<2048, b256, 0, stream>>>(outw,   owh, owl, (long)(nOW/4));
  split_many<<<2048, b256, 0, stream>>>(e1w,    e1h, e1l, (long)(nE1/4));
  split_many<<<2048, b256, 0, stream>>>(e2w,    e2h, e2l, (long)(nE2/4));

  // patch: MT=49 -> MTg=13 (MG=4), NB=6 -> NBg=3 (NG=2); grid 8*13*3
  gemm_split<4,2><<<dim3(8*13*3), b256, 0, stream>>>(xh, xl, cwh, cwl,
      conv_b, nullptr, xt, pos, nullptr, nullptr,
      nullptr, nullptr, nullptr, nullptr, 13, 3, 6272, D_MODEL, 768);
  cls_init<<<dim3(BATCH), b256, 0, stream>>>(cls_tk, pos, xt);

  for (int i = 0; i < DEPTH_N; i++){
    ln_kernel<<<dim3(NTOK), b256, 0, stream>>>(xt, D_MODEL,
        ln1w + (size_t)i*D_MODEL, ln1b + (size_t)i*D_MODEL, y, D_MODEL, yh, yl);
    // qkv: MT=50 -> MTg=13 (MG=4), NB=18 -> NBg=9 (NG=2); W-slice 3.5MB L2-res
    gemm_split<0,2><<<dim3(8*13*9), b256, 0, stream>>>(yh, yl,
        qwh + (size_t)i*3*D_MODEL*D_MODEL, qwl + (size_t)i*3*D_MODEL*D_MODEL,
        qkvb + (size_t)i*3*D_MODEL, nullptr, qkv, nullptr, nullptr, nullptr,
        nullptr, nullptr, nullptr, nullptr, 13, 9, NTOK, 3*D_MODEL, D_MODEL);
    attn_f32<<<dim3(4, NHEAD, BATCH), b256, 0, stream>>>(qkv, ch, cl);
    // out: MT=50 -> MTg=13, NB=6 -> NBg=3 (NG=2); W-slice 1.2MB
    gemm_split<1,2><<<dim3(8*13*3), b256, 0, stream>>>(ch, cl,
        owh + (size_t)i*D_MODEL*D_MODEL, owl + (size_t)i*D_MODEL*D_MODEL,
        outb + (size_t)i*D_MODEL, xt, xt, nullptr, nullptr, nullptr,
        nullptr, nullptr, nullptr, nullptr, 13, 3, NTOK, D_MODEL, D_MODEL);
    ln_kernel<<<dim3(NTOK), b256, 0, stream>>>(xt, D_MODEL,
        ln2w + (size_t)i*D_MODEL, ln2b + (size_t)i*D_MODEL, y, D_MODEL, yh, yl);
    zero_counts<<<1, 64, 0, stream>>>(counts);
    gate_kernel<<<dim3(NTOK), b256, 0, stream>>>(y,
        gatew + (size_t)i*NEXP*D_MODEL, gateb + (size_t)i*NEXP, eidx, counts);
    offsets_kernel<<<1, 64, 0, stream>>>(counts, offs, cursor, tiles);
    scatter_kernel<<<dim3((NTOK+255)/256), b256, 0, stream>>>(eidx, cursor, toks);
    // e1: MTmax=53 -> MTg=27 (MG=2), NB=24 -> NBg=6 (NG=4); W-slice 2.35MB
    gemm_split<2,4><<<dim3(8*27*6), b256, 0, stream>>>(yh, yl,
        e1h + (size_t)i*NEXP*HID_N*D_MODEL, e1l + (size_t)i*NEXP*HID_N*D_MODEL,
        e1b + (size_t)i*NEXP*HID_N, nullptr, nullptr, nullptr, h1h, h1l,
        toks, counts, offs, tiles, 27, 6, NTOK, HID_N, D_MODEL);
    // e2: MTmax=53 -> MTg=14 (MG=4), NB=6 -> NBg=3 (NG=2); W-slice 4.7MB/4=1.2MB... 3 panels*1.57MB
    gemm_split<3,2><<<dim3(8*14*3), b256, 0, stream>>>(h1h, h1l,
        e2h + (size_t)i*NEXP*D_MODEL*HID_N, e2l + (size_t)i*NEXP*D_MODEL*HID_N,
        e2b + (size_t)i*NEXP*D_MODEL, nullptr, xt, nullptr, nullptr, nullptr,
        toks, counts, offs, tiles, 14, 3, NTOK, D_MODEL, HID_N);
  }

  ln_kernel<<<dim3(BATCH), b256, 0, stream>>>(xt, (size_t)SEQ*D_MODEL, fnw, fnb,
      clsln, D_MODEL, nullptr, nullptr);
  gemm_f32<<<dim3(1, 16), b256, 0, stream>>>(clsln, headw, headb, nullptr, out, BATCH, 1000, D_MODEL);
}